// Round 10
// baseline (902.230 us; speedup 1.0000x reference)
//
#include <hip/hip_runtime.h>
#include <hip/hip_bf16.h>

// Problem constants (ResNet-50 CBP head)
#define BATCH 8
#define CH    2048
#define LSP   784          // H*W = 28*28
#define KPAD  800          // pad K to 25*32 for MFMA k-steps
#define KSTEPS (KPAD/32)   // 25
#define DDIM  8192         // count-sketch dim (power of 2)
#define NCLS  200
#define NTILE 16           // 2048/128 tiles per dim
#define NPAIR 136          // NTILE*(NTILE+1)/2 symmetric tile pairs
#define NSLOT 68           // part slots per batch (2 blocks/slot)

typedef _Float16 f16x8 __attribute__((ext_vector_type(8)));
typedef _Float16 f16x4 __attribute__((ext_vector_type(4)));
typedef float    f32x4 __attribute__((ext_vector_type(4)));

#define FATOMIC(p, v) unsafeAtomicAdd((p), (v))

// ---------------------------------------------------------------------------
// Kernel 1: convert x (fp32 [B,C,784]) to fp16 [B,C,KPAD] (zero-pad K).
// fp16 (11-bit mantissa) keeps Gram rel-err ~5e-4 -> single MFMA, no hi/lo.
// Also zero-inits part/norm, seeds logits with bias.
// ---------------------------------------------------------------------------
__global__ __launch_bounds__(256) void split_kernel(
    const float* __restrict__ x,
    _Float16* __restrict__ xh,
    float* __restrict__ part, float* __restrict__ norm,
    const float* __restrict__ bc, float* __restrict__ out)
{
    int idx = blockIdx.x * 256 + threadIdx.x;          // vec4 index
    if (idx < NSLOT * BATCH * DDIM / 4)                // zero part (float4)
        *(float4*)&part[idx * 4] = make_float4(0.f, 0.f, 0.f, 0.f);
    if (idx < BATCH) norm[idx] = 0.0f;
    if (idx < BATCH * NCLS) out[idx] = bc[idx % NCLS]; // bias-seed logits
    if (idx >= BATCH * CH * KPAD / 4) return;
    int v  = idx * 4;
    int bc_ = v / KPAD;
    int l  = v - bc_ * KPAD;                           // multiple of 4
    float4 xv = make_float4(0.f, 0.f, 0.f, 0.f);
    if (l < LSP)                                       // LSP%4==0: uniform per vec
        xv = *(const float4*)&x[(size_t)bc_ * LSP + l];
    f16x4 hv;
    hv[0] = (_Float16)xv.x; hv[1] = (_Float16)xv.y;
    hv[2] = (_Float16)xv.z; hv[3] = (_Float16)xv.w;
    *(f16x4*)&xh[v] = hv;
}

// ---------------------------------------------------------------------------
// Kernel 2: symmetric Gram tile (fp16 MFMA) + SPLIT-PIPE count-sketch scatter.
// grid = 1088: batch = id&7 (one batch per XCD), pair = id>>3.
// Scatter is the roofline (~205 cyc per 64-lane random ds_add_f32): forward
// entries go to LDS bins (~half the ops), mirror entries go DIRECTLY to the
// global part slot via fire-and-forget global_atomic_add_f32 (L2 atomic
// units = a different pipe, concurrent with LDS + MFMA).
// ---------------------------------------------------------------------------
__device__ __forceinline__ void stage_tile(
    const _Float16* __restrict__ src, size_t rowbase_elems,
    unsigned short* lds_tile, int wv, int lane, int k0)
{
#pragma unroll
    for (int half = 0; half < 2; ++half) {
        int ch  = wv * 2 + half;                       // 0..7 chunk of 8KB tile
        int row = ch * 16 + (lane >> 2);
        int kg  = (lane & 3) ^ ((lane >> 3) & 3);      // XOR swizzle (row>>1)&3
        const _Float16* g = src + rowbase_elems
            + (size_t)row * KPAD + k0 + kg * 8;
        __builtin_amdgcn_global_load_lds(
            (__attribute__((address_space(1))) void*)g,
            (__attribute__((address_space(3))) void*)(lds_tile + ch * 512),
            16, 0, 0);
    }
}

__global__ __launch_bounds__(256, 3) void gram_scatter_kernel(
    const _Float16* __restrict__ xh,
    const int*   __restrict__ h1, const float* __restrict__ s1,
    const int*   __restrict__ h2, const float* __restrict__ s2,
    float* __restrict__ part)
{
    __shared__ __align__(16) unsigned short smA[128 * 32];   // 8 KB fp16 tile
    __shared__ __align__(16) unsigned short smB[128 * 32];   // 8 KB
    __shared__ float bins[DDIM];                             // 32 KB
    __shared__ float4 metaA[128];                            // 2 KB

    const int tid  = threadIdx.x;
    const int lane = tid & 63;
    const int wv   = tid >> 6;
    const int b    = blockIdx.x & 7;       // batch in low bits -> one batch/XCD
    const int pidx = blockIdx.x >> 3;      // triangular pair index

    // Triangular decode: pidx in [0,136) -> (tM, tN), tM <= tN, row-major
    int tM = 0, tN = 0;
    {
        int i = pidx;
#pragma unroll 1
        for (int t = 0; t < NTILE; ++t) {
            int cnt = NTILE - t;
            if (i < cnt) { tM = t; tN = t + i; break; }
            i -= cnt;
        }
    }
    const bool diag = (tM == tN);

    for (int i = tid; i < DDIM; i += 256) bins[i] = 0.0f;
    // (first __syncthreads inside k-loop orders this before any scatter)

    const int wrow = (wv >> 1) * 64;    // wave's 64x64 subtile origin
    const int wcol = (wv & 1) * 64;

    const size_t rowbaseA = ((size_t)b * CH + (size_t)tM * 128) * KPAD;
    const size_t rowbaseB = ((size_t)b * CH + (size_t)tN * 128) * KPAD;

    const unsigned short* fragB = diag ? smA : smB;

    f32x4 acc[4][4];
    const f32x4 zv = {0.0f, 0.0f, 0.0f, 0.0f};
#pragma unroll
    for (int mi = 0; mi < 4; ++mi)
#pragma unroll
        for (int ni = 0; ni < 4; ++ni) acc[mi][ni] = zv;

    // fragment LDS offset: (row)*32 + fxor; XOR term is a per-lane constant
    const int fxor = (((lane >> 4) ^ ((lane >> 1) & 3)) << 3);
    const int rsel = lane & 15;

    for (int ks = 0; ks < KSTEPS; ++ks) {
        const int k0 = ks * 32;
        stage_tile(xh, rowbaseA, smA, wv, lane, k0);
        if (!diag) stage_tile(xh, rowbaseB, smB, wv, lane, k0);
        __syncthreads();

        f16x8 ah[4], bh[4];
#pragma unroll
        for (int i = 0; i < 4; ++i) {
            int offa = (wrow + i * 16 + rsel) * 32 + fxor;
            ah[i] = *(const f16x8*)&smA[offa];
            int offb = (wcol + i * 16 + rsel) * 32 + fxor;
            bh[i] = *(const f16x8*)&fragB[offb];
        }
#pragma unroll
        for (int mi = 0; mi < 4; ++mi)
#pragma unroll
            for (int ni = 0; ni < 4; ++ni)
                acc[mi][ni] = __builtin_amdgcn_mfma_f32_16x16x32_f16(ah[mi], bh[ni], acc[mi][ni], 0, 0, 0);
        __syncthreads();
    }

    // Stage scatter meta for this tile's 128 c1-rows into LDS.
    if (tid < 128) {
        int c1 = tM * 128 + tid;
        metaA[tid] = make_float4(s1[c1], __int_as_float(h1[c1]),
                                 s2[c1], __int_as_float(h2[c1]));
    }
    __syncthreads();

    // The block's global part slot (also the flush target).
    float* pb = part + ((size_t)((pidx % NSLOT) * BATCH + b) * DDIM);

    // Scatter the 128x128 Gram tile.  C/D layout (m89-verified):
    // col = lane&15, row = (lane>>4)*4 + reg.
    // Forward entry  -> LDS bins (ds_add_f32).
    // Mirror entry   -> global part slot (global_atomic_add_f32, other pipe).
    const int c2b = tN * 128 + wcol + (lane & 15);
    const int rowsel = wrow + ((lane >> 4) << 2);
    int   h1c[4], h2c[4]; float s1c[4], s2c[4];
#pragma unroll
    for (int ni = 0; ni < 4; ++ni) {
        int c2 = c2b + ni * 16;
        h1c[ni] = h1[c2]; s1c[ni] = s1[c2];
        h2c[ni] = h2[c2]; s2c[ni] = s2[c2];
    }
#pragma unroll
    for (int mi = 0; mi < 4; ++mi) {
#pragma unroll
        for (int r = 0; r < 4; ++r) {
            float4 m = metaA[rowsel + mi * 16 + r];    // one ds_read_b128
            const float s1r = m.x, s2r = m.z;
            const int h1r = __float_as_int(m.y);
            const int h2r = __float_as_int(m.w);
#pragma unroll
            for (int ni = 0; ni < 4; ++ni) {
                float g = acc[mi][ni][r];
                FATOMIC(&bins[(h1r + h2c[ni]) & (DDIM - 1)], s1r * s2c[ni] * g);
                if (!diag)
                    FATOMIC(&pb[(h1c[ni] + h2r) & (DDIM - 1)], s1c[ni] * s2r * g);
            }
        }
    }

    __syncthreads();   // all LDS scatters into bins complete

    // Flush bins to the part slot (2 blocks/slot, rotated order).
    const int rot = (blockIdx.x & 31) << 8;
    for (int i = tid; i < DDIM; i += 256) {
        int j = (i + rot) & (DDIM - 1);
        float v = bins[j];
        if (v != 0.0f) FATOMIC(&pb[j], v);
    }
}

// ---------------------------------------------------------------------------
// Kernel 3: y[b,d] = sum over 68 part slots; accumulate norm[b] += sum|y|.
// grid 64 x 256: one float4 of d per thread.
// ---------------------------------------------------------------------------
__global__ __launch_bounds__(256) void reduce_kernel(
    const float* __restrict__ part, float* __restrict__ y,
    float* __restrict__ norm)
{
    const int tid = threadIdx.x;
    const int b  = blockIdx.x >> 3;
    const int d0 = (((blockIdx.x & 7) * 256) + tid) * 4;   // float4 slice
    float4 s = make_float4(0.f, 0.f, 0.f, 0.f);
#pragma unroll 4
    for (int p = 0; p < NSLOT; ++p) {
        float4 v = *(const float4*)&part[((size_t)p * BATCH + b) * DDIM + d0];
        s.x += v.x; s.y += v.y; s.z += v.z; s.w += v.w;
    }
    *(float4*)&y[(size_t)b * DDIM + d0] = s;
    float ab = fabsf(s.x) + fabsf(s.y) + fabsf(s.z) + fabsf(s.w);
    __shared__ float red[256];
    red[tid] = ab;
    __syncthreads();
    for (int st = 128; st > 0; st >>= 1) {
        if (tid < st) red[tid] += red[tid + st];
        __syncthreads();
    }
    if (tid == 0) FATOMIC(&norm[b], red[0]);   // sum|y| == sum feat_unnorm^2
}

// ---------------------------------------------------------------------------
// Kernel 4: fused signed-sqrt + L2-normalize + classifier GEMV.
// grid 64: block j owns d in [128j, 128j+128) for all batches.
// ---------------------------------------------------------------------------
__global__ __launch_bounds__(256) void logit_kernel(
    const float* __restrict__ y, const float* __restrict__ norm,
    const float* __restrict__ W, float* __restrict__ out)
{
    const int j = blockIdx.x;
    const int tid = threadIdx.x;
    __shared__ float fs[BATCH][128];                   // 4 KB
    for (int i = tid; i < BATCH * 128; i += 256) {
        int bb = i >> 7, dd = i & 127;
        float v = y[(size_t)bb * DDIM + j * 128 + dd];
        float inv = 1.0f / fmaxf(sqrtf(norm[bb]), 1e-12f);
        float f = copysignf(sqrtf(fabsf(v)), v) * inv;
        fs[bb][dd] = f;
        out[BATCH * NCLS + (size_t)bb * DDIM + j * 128 + dd] = f;
    }
    __syncthreads();
    if (tid < NCLS) {
        float a[BATCH];
#pragma unroll
        for (int bb = 0; bb < BATCH; ++bb) a[bb] = 0.0f;
        for (int dd = 0; dd < 128; ++dd) {
            float w = W[(size_t)(j * 128 + dd) * NCLS + tid];
#pragma unroll
            for (int bb = 0; bb < BATCH; ++bb) a[bb] += fs[bb][dd] * w;
        }
#pragma unroll
        for (int bb = 0; bb < BATCH; ++bb)
            FATOMIC(&out[bb * NCLS + tid], a[bb]);
    }
}

// ---------------------------------------------------------------------------
extern "C" void kernel_launch(void* const* d_in, const int* in_sizes, int n_in,
                              void* d_out, int out_size, void* d_ws, size_t ws_size,
                              hipStream_t stream)
{
    const float* x  = (const float*)d_in[0];
    const float* s1 = (const float*)d_in[1];
    const float* s2 = (const float*)d_in[2];
    const float* W  = (const float*)d_in[3];
    const float* bc = (const float*)d_in[4];
    const int*   h1 = (const int*)d_in[5];
    const int*   h2 = (const int*)d_in[6];
    float* out = (float*)d_out;

    // ws layout: part (17.8MB) | y (256KB) | norm (128B) | xh (26.2MB) ~ 44.3MB
    char* ws = (char*)d_ws;
    float* part = (float*)ws;
    const size_t partbytes = (size_t)NSLOT * BATCH * DDIM * sizeof(float);
    float* y    = (float*)(ws + partbytes);
    const size_t ybytes = (size_t)BATCH * DDIM * sizeof(float);
    float* norm = (float*)(ws + partbytes + ybytes);
    _Float16* xh = (_Float16*)(ws + partbytes + ybytes + 128);

    split_kernel<<<(BATCH * CH * KPAD / 4 + 255) / 256, 256, 0, stream>>>(
        x, xh, part, norm, bc, out);

    gram_scatter_kernel<<<NPAIR * BATCH, 256, 0, stream>>>(
        xh, h1, s1, h2, s2, part);

    reduce_kernel<<<64, 256, 0, stream>>>(part, y, norm);

    logit_kernel<<<64, 256, 0, stream>>>(y, norm, W, out);
}

// Round 11
// 360.595 us; speedup vs baseline: 2.5021x; 2.5021x over previous
//
#include <hip/hip_runtime.h>
#include <hip/hip_bf16.h>

// Problem constants (ResNet-50 CBP head)
#define BATCH 8
#define CH    2048
#define LSP   784          // H*W = 28*28
#define KPAD  800          // pad K to 25*32 for MFMA k-steps
#define KSTEPS (KPAD/32)   // 25
#define DDIM  8192         // count-sketch dim (power of 2)
#define NCLS  200
#define NTILE 16           // 2048/128 tiles per dim
#define NPAIR 136          // NTILE*(NTILE+1)/2 symmetric tile pairs
#define NSLOT 136          // one part slot per pair -> store-flush, no atomics

typedef _Float16 f16x8 __attribute__((ext_vector_type(8)));
typedef _Float16 f16x4 __attribute__((ext_vector_type(4)));
typedef float    f32x4 __attribute__((ext_vector_type(4)));

#define FATOMIC(p, v) unsafeAtomicAdd((p), (v))

// ---------------------------------------------------------------------------
// Kernel 1: convert x (fp32 [B,C,784]) to fp16 [B,C,KPAD] (zero-pad K).
// fp16 (11-bit mantissa) keeps Gram rel-err ~5e-4 -> single MFMA, no hi/lo.
// No part zeroing needed (store-flush); zero norm, seed logits with bias.
// ---------------------------------------------------------------------------
__global__ __launch_bounds__(256) void split_kernel(
    const float* __restrict__ x,
    _Float16* __restrict__ xh,
    float* __restrict__ norm,
    const float* __restrict__ bc, float* __restrict__ out)
{
    int idx = blockIdx.x * 256 + threadIdx.x;          // vec4 index
    if (idx < BATCH) norm[idx] = 0.0f;
    if (idx < BATCH * NCLS) out[idx] = bc[idx % NCLS]; // bias-seed logits
    if (idx >= BATCH * CH * KPAD / 4) return;
    int v  = idx * 4;
    int bc_ = v / KPAD;
    int l  = v - bc_ * KPAD;                           // multiple of 4
    float4 xv = make_float4(0.f, 0.f, 0.f, 0.f);
    if (l < LSP)                                       // LSP%4==0: uniform per vec
        xv = *(const float4*)&x[(size_t)bc_ * LSP + l];
    f16x4 hv;
    hv[0] = (_Float16)xv.x; hv[1] = (_Float16)xv.y;
    hv[2] = (_Float16)xv.z; hv[3] = (_Float16)xv.w;
    *(f16x4*)&xh[v] = hv;
}

// ---------------------------------------------------------------------------
// Kernel 2: symmetric Gram tile (fp16 MFMA) + LDS count-sketch scatter.
// grid = 1088: batch = id&7 (one batch per XCD), pair = id>>3.
// Scatter roofline: ds_add_f32 RMW throughput ~2.9 cyc/lane-op (measured;
// not bank conflicts, not CAS — R6/R8/R10 falsified those).  Both forward
// and mirror entries go to LDS bins (R10: global random atomics = 0.5 GB
// HBM writes, 3.4x slower).  Flush = plain float4 stores to the pair's
// private part slot (no atomics, no zero-init).
// ---------------------------------------------------------------------------
__device__ __forceinline__ void stage_tile(
    const _Float16* __restrict__ src, size_t rowbase_elems,
    unsigned short* lds_tile, int wv, int lane, int k0)
{
#pragma unroll
    for (int half = 0; half < 2; ++half) {
        int ch  = wv * 2 + half;                       // 0..7 chunk of 8KB tile
        int row = ch * 16 + (lane >> 2);
        int kg  = (lane & 3) ^ ((lane >> 3) & 3);      // XOR swizzle (row>>1)&3
        const _Float16* g = src + rowbase_elems
            + (size_t)row * KPAD + k0 + kg * 8;
        __builtin_amdgcn_global_load_lds(
            (__attribute__((address_space(1))) void*)g,
            (__attribute__((address_space(3))) void*)(lds_tile + ch * 512),
            16, 0, 0);
    }
}

__global__ __launch_bounds__(256, 3) void gram_scatter_kernel(
    const _Float16* __restrict__ xh,
    const int*   __restrict__ h1, const float* __restrict__ s1,
    const int*   __restrict__ h2, const float* __restrict__ s2,
    float* __restrict__ part)
{
    __shared__ __align__(16) unsigned short smA[128 * 32];   // 8 KB fp16 tile
    __shared__ __align__(16) unsigned short smB[128 * 32];   // 8 KB
    __shared__ __align__(16) float bins[DDIM];               // 32 KB
    __shared__ float4 metaA[128];                            // 2 KB

    const int tid  = threadIdx.x;
    const int lane = tid & 63;
    const int wv   = tid >> 6;
    const int b    = blockIdx.x & 7;       // batch in low bits -> one batch/XCD
    const int pidx = blockIdx.x >> 3;      // triangular pair index

    // Triangular decode: pidx in [0,136) -> (tM, tN), tM <= tN, row-major
    int tM = 0, tN = 0;
    {
        int i = pidx;
#pragma unroll 1
        for (int t = 0; t < NTILE; ++t) {
            int cnt = NTILE - t;
            if (i < cnt) { tM = t; tN = t + i; break; }
            i -= cnt;
        }
    }
    const bool diag = (tM == tN);

    for (int i = tid; i < DDIM; i += 256) bins[i] = 0.0f;
    // (first __syncthreads inside k-loop orders this before any scatter)

    const int wrow = (wv >> 1) * 64;    // wave's 64x64 subtile origin
    const int wcol = (wv & 1) * 64;

    const size_t rowbaseA = ((size_t)b * CH + (size_t)tM * 128) * KPAD;
    const size_t rowbaseB = ((size_t)b * CH + (size_t)tN * 128) * KPAD;

    const unsigned short* fragB = diag ? smA : smB;

    f32x4 acc[4][4];
    const f32x4 zv = {0.0f, 0.0f, 0.0f, 0.0f};
#pragma unroll
    for (int mi = 0; mi < 4; ++mi)
#pragma unroll
        for (int ni = 0; ni < 4; ++ni) acc[mi][ni] = zv;

    // fragment LDS offset: (row)*32 + fxor; XOR term is a per-lane constant
    const int fxor = (((lane >> 4) ^ ((lane >> 1) & 3)) << 3);
    const int rsel = lane & 15;

    for (int ks = 0; ks < KSTEPS; ++ks) {
        const int k0 = ks * 32;
        stage_tile(xh, rowbaseA, smA, wv, lane, k0);
        if (!diag) stage_tile(xh, rowbaseB, smB, wv, lane, k0);
        __syncthreads();

        f16x8 ah[4], bh[4];
#pragma unroll
        for (int i = 0; i < 4; ++i) {
            int offa = (wrow + i * 16 + rsel) * 32 + fxor;
            ah[i] = *(const f16x8*)&smA[offa];
            int offb = (wcol + i * 16 + rsel) * 32 + fxor;
            bh[i] = *(const f16x8*)&fragB[offb];
        }
#pragma unroll
        for (int mi = 0; mi < 4; ++mi)
#pragma unroll
            for (int ni = 0; ni < 4; ++ni)
                acc[mi][ni] = __builtin_amdgcn_mfma_f32_16x16x32_f16(ah[mi], bh[ni], acc[mi][ni], 0, 0, 0);
        __syncthreads();
    }

    // Stage scatter meta for this tile's 128 c1-rows into LDS.
    if (tid < 128) {
        int c1 = tM * 128 + tid;
        metaA[tid] = make_float4(s1[c1], __int_as_float(h1[c1]),
                                 s2[c1], __int_as_float(h2[c1]));
    }
    __syncthreads();

    // Scatter the 128x128 Gram tile into the LDS histogram.
    // C/D layout (m89-verified): col = lane&15, row = (lane>>4)*4 + reg
    // Off-diagonal pair: each entry contributes twice (G symmetric).
    const int c2b = tN * 128 + wcol + (lane & 15);
    const int rowsel = wrow + ((lane >> 4) << 2);
    int   h1c[4], h2c[4]; float s1c[4], s2c[4];
#pragma unroll
    for (int ni = 0; ni < 4; ++ni) {
        int c2 = c2b + ni * 16;
        h1c[ni] = h1[c2]; s1c[ni] = s1[c2];
        h2c[ni] = h2[c2]; s2c[ni] = s2[c2];
    }
#pragma unroll
    for (int mi = 0; mi < 4; ++mi) {
#pragma unroll
        for (int r = 0; r < 4; ++r) {
            float4 m = metaA[rowsel + mi * 16 + r];    // one ds_read_b128
            const float s1r = m.x, s2r = m.z;
            const int h1r = __float_as_int(m.y);
            const int h2r = __float_as_int(m.w);
#pragma unroll
            for (int ni = 0; ni < 4; ++ni) {
                float g = acc[mi][ni][r];
                FATOMIC(&bins[(h1r + h2c[ni]) & (DDIM - 1)], s1r * s2c[ni] * g);
                if (!diag)
                    FATOMIC(&bins[(h1c[ni] + h2r) & (DDIM - 1)], s1c[ni] * s2r * g);
            }
        }
    }

    __syncthreads();   // all scatters into bins complete

    // Store-flush: this pair's private slot, coalesced float4, no atomics.
    float4* pb4 = (float4*)(part + ((size_t)(pidx * BATCH + b) * DDIM));
    const float4* bins4 = (const float4*)bins;
    for (int i = tid; i < DDIM / 4; i += 256)
        pb4[i] = bins4[i];
}

// ---------------------------------------------------------------------------
// Kernel 3: y[b,d] = sum over 136 part slots; accumulate norm[b] += sum|y|.
// grid 64 x 256: one float4 of d per thread; 35.7 MB read ~6 us.
// ---------------------------------------------------------------------------
__global__ __launch_bounds__(256) void reduce_kernel(
    const float* __restrict__ part, float* __restrict__ y,
    float* __restrict__ norm)
{
    const int tid = threadIdx.x;
    const int b  = blockIdx.x >> 3;
    const int d0 = (((blockIdx.x & 7) * 256) + tid) * 4;   // float4 slice
    float4 s = make_float4(0.f, 0.f, 0.f, 0.f);
#pragma unroll 8
    for (int p = 0; p < NSLOT; ++p) {
        float4 v = *(const float4*)&part[((size_t)p * BATCH + b) * DDIM + d0];
        s.x += v.x; s.y += v.y; s.z += v.z; s.w += v.w;
    }
    *(float4*)&y[(size_t)b * DDIM + d0] = s;
    float ab = fabsf(s.x) + fabsf(s.y) + fabsf(s.z) + fabsf(s.w);
    __shared__ float red[256];
    red[tid] = ab;
    __syncthreads();
    for (int st = 128; st > 0; st >>= 1) {
        if (tid < st) red[tid] += red[tid + st];
        __syncthreads();
    }
    if (tid == 0) FATOMIC(&norm[b], red[0]);   // sum|y| == sum feat_unnorm^2
}

// ---------------------------------------------------------------------------
// Kernel 4: fused signed-sqrt + L2-normalize + classifier GEMV.
// grid 64: block j owns d in [128j, 128j+128) for all batches.
// ---------------------------------------------------------------------------
__global__ __launch_bounds__(256) void logit_kernel(
    const float* __restrict__ y, const float* __restrict__ norm,
    const float* __restrict__ W, float* __restrict__ out)
{
    const int j = blockIdx.x;
    const int tid = threadIdx.x;
    __shared__ float fs[BATCH][128];                   // 4 KB
    for (int i = tid; i < BATCH * 128; i += 256) {
        int bb = i >> 7, dd = i & 127;
        float v = y[(size_t)bb * DDIM + j * 128 + dd];
        float inv = 1.0f / fmaxf(sqrtf(norm[bb]), 1e-12f);
        float f = copysignf(sqrtf(fabsf(v)), v) * inv;
        fs[bb][dd] = f;
        out[BATCH * NCLS + (size_t)bb * DDIM + j * 128 + dd] = f;
    }
    __syncthreads();
    if (tid < NCLS) {
        float a[BATCH];
#pragma unroll
        for (int bb = 0; bb < BATCH; ++bb) a[bb] = 0.0f;
        for (int dd = 0; dd < 128; ++dd) {
            float w = W[(size_t)(j * 128 + dd) * NCLS + tid];
#pragma unroll
            for (int bb = 0; bb < BATCH; ++bb) a[bb] += fs[bb][dd] * w;
        }
#pragma unroll
        for (int bb = 0; bb < BATCH; ++bb)
            FATOMIC(&out[bb * NCLS + tid], a[bb]);
    }
}

// ---------------------------------------------------------------------------
extern "C" void kernel_launch(void* const* d_in, const int* in_sizes, int n_in,
                              void* d_out, int out_size, void* d_ws, size_t ws_size,
                              hipStream_t stream)
{
    const float* x  = (const float*)d_in[0];
    const float* s1 = (const float*)d_in[1];
    const float* s2 = (const float*)d_in[2];
    const float* W  = (const float*)d_in[3];
    const float* bc = (const float*)d_in[4];
    const int*   h1 = (const int*)d_in[5];
    const int*   h2 = (const int*)d_in[6];
    float* out = (float*)d_out;

    // ws layout: part (35.7MB) | y (256KB) | norm (128B) | xh (26.2MB) ~ 62.2MB
    char* ws = (char*)d_ws;
    float* part = (float*)ws;
    const size_t partbytes = (size_t)NSLOT * BATCH * DDIM * sizeof(float);
    float* y    = (float*)(ws + partbytes);
    const size_t ybytes = (size_t)BATCH * DDIM * sizeof(float);
    float* norm = (float*)(ws + partbytes + ybytes);
    _Float16* xh = (_Float16*)(ws + partbytes + ybytes + 128);

    split_kernel<<<(BATCH * CH * KPAD / 4 + 255) / 256, 256, 0, stream>>>(
        x, xh, norm, bc, out);

    gram_scatter_kernel<<<NPAIR * BATCH, 256, 0, stream>>>(
        xh, h1, s1, h2, s2, part);

    reduce_kernel<<<64, 256, 0, stream>>>(part, y, norm);

    logit_kernel<<<64, 256, 0, stream>>>(y, norm, W, out);
}